// Round 14
// baseline (260.073 us; speedup 1.0000x reference)
//
#include <hip/hip_runtime.h>
#include <math.h>

#define N_NODES 10000
#define N_EDGES 320000
#define N_AUG   (N_EDGES + N_NODES)
#define CPK_CAP 330752
#define HID     256

typedef short short8 __attribute__((ext_vector_type(8)));
typedef float floatx16 __attribute__((ext_vector_type(16)));

// bf16 round-to-nearest-even, as the low 16 bits of a uint
static __device__ __forceinline__ unsigned bf16rne(float f) {
  unsigned u = __float_as_uint(f);
  return (u + 0x7FFFu + ((u >> 16) & 1u)) >> 16;
}

// ------- fused front kernel ------------------------------------------------
// blocks [0,1250): degree+rank+attr-sum via ONE packed 64-bit atomic per edge
// blocks [1250,1442): weight conversion (W1|W2 -> Wt bf16 T, Wp1 -> Wp1t)
__global__ void __launch_bounds__(256) k_front(
    const int* __restrict__ dst, const float* __restrict__ ea,
    unsigned long long* __restrict__ pdeg, int* __restrict__ rank,
    const float* __restrict__ W1, const float* __restrict__ W2,
    const float* __restrict__ Wp1,
    unsigned short* __restrict__ Wt, unsigned short* __restrict__ Wp1t) {
  __shared__ float tile[32][33];
  int bi = blockIdx.x;
  int t = threadIdx.x;
  if (bi < 1250) {
    int e = bi * 256 + t;
    int d = dst[e];
    int fx = __float2int_rn(ea[e] * 262144.0f);       // 2^18 scale
    unsigned long long pk = 0x100000000ull
                          + (unsigned long long)(unsigned)(fx + 2097152);
    unsigned long long old = atomicAdd(&pdeg[d], pk);
    rank[e] = (int)(old >> 32);
    return;
  }
  int pb = bi - 1250;
  int z = pb >> 6;
  int rem = pb & 63;
  int kb = (rem & 7) * 32, nb = (rem >> 3) * 32;
  int tx = t & 31, ty = t >> 5;
  if (z < 2) {
    const float* W = z ? W2 : W1;
    int rowoff = z * 256;
    #pragma unroll
    for (int rep = 0; rep < 4; rep++)
      tile[ty + 8*rep][tx] = W[(kb + ty + 8*rep)*HID + nb + tx];
    __syncthreads();
    #pragma unroll
    for (int rep = 0; rep < 4; rep++) {
      int n = nb + ty + 8*rep;
      Wt[(rowoff + n)*256 + kb + tx] = (unsigned short)bf16rne(tile[tx][ty + 8*rep]);
    }
  } else {
    if (nb >= 128) return;
    #pragma unroll
    for (int rep = 0; rep < 4; rep++)
      tile[ty + 8*rep][tx] = Wp1[(kb + ty + 8*rep)*128 + nb + tx];
    __syncthreads();
    #pragma unroll
    for (int rep = 0; rep < 4; rep++) {
      int n = nb + ty + 8*rep;
      Wp1t[n*256 + kb + tx] = (unsigned short)bf16rne(tile[tx][ty + 8*rep]);
    }
  }
}

// ------- exclusive scan of (deg+1) over 10000 nodes (parallel), + loop_attr --
__global__ void __launch_bounds__(256) k_scan(
    const unsigned long long* __restrict__ pdeg,
    int* __restrict__ offs, float* __restrict__ lattr) {
  __shared__ int wsum[4];
  int t = threadIdx.x;
  int base = t * 40;
  int s = 0;
  for (int i = 0; i < 40; i++) {
    int n = base + i;
    if (n < N_NODES) s += (int)(pdeg[n] >> 32) + 1;
  }
  int v = s;
  #pragma unroll
  for (int d = 1; d < 64; d <<= 1) {
    int u = __shfl_up(v, d);
    if ((t & 63) >= d) v += u;
  }
  if ((t & 63) == 63) wsum[t >> 6] = v;
  __syncthreads();
  int wb = 0;
  for (int i = 0; i < (t >> 6); i++) wb += wsum[i];
  int run = wb + v - s;
  for (int i = 0; i < 40; i++) {
    int n = base + i;
    if (n < N_NODES) {
      offs[n] = run;
      unsigned long long pv = pdeg[n];
      int d = (int)(pv >> 32);
      run += d + 1;
      int lower = (int)(pv & 0xFFFFFFFFull);
      float asum = (float)(lower - d * 2097152) * (1.f / 262144.f);
      lattr[n] = asum / (float)max(d, 1);
    }
  }
  if (t == 255) offs[N_NODES] = wb + v;
}

// ------- scatter edges into CSR by dst (atomic-free via rank); zero pad -----
__global__ void k_scatter(const int* __restrict__ src, const int* __restrict__ dst,
                          const float* __restrict__ ea, const float* __restrict__ lattr,
                          const int* __restrict__ offs, const int* __restrict__ rank,
                          int2* __restrict__ cpk) {
  int e = blockIdx.x * blockDim.x + threadIdx.x;
  if (e >= N_AUG) {
    if (e < CPK_CAP) cpk[e] = make_int2(0, 0);   // pad: row-0, av=0
    return;
  }
  int pos, s; float a;
  if (e < N_EDGES) {
    s = src[e];
    int d = dst[e];
    a = ea[e];
    pos = offs[d] + rank[e];
  } else {
    s = e - N_EDGES;
    a = lattr[s];
    pos = offs[s + 1] - 1;    // self-loop last in segment
  }
  cpk[pos] = make_int2(s, __float_as_int(a));
}

// ============================ conv1 =========================================
// 1 node / 128-thread block (2 waves), 2 channels per lane.
// Head (64ch) = one 32-lane group inside a wave -> shuffle-only softmax.
#define C1_EDGE2(xs, av, l0, l1, p)                                             \
  {                                                                             \
    l0 = fmaf(xs.x,wl0.x, fmaf(xs.y,wl1.x, fmaf(xs.z,wl2.x, fmaf(xs.w,wl3.x, blv.x)))); \
    l1 = fmaf(xs.x,wl0.y, fmaf(xs.y,wl1.y, fmaf(xs.z,wl2.y, fmaf(xs.w,wl3.y, blv.y)))); \
    float m0 = l0 + fmaf(av, we2.x, r40); m0 = fmaxf(m0, 0.2f*m0);              \
    float m1 = l1 + fmaf(av, we2.y, r41); m1 = fmaxf(m1, 0.2f*m1);              \
    p = m0*at2.x + m1*at2.y;                                                    \
  }

#define C1_BODY8()                                                              \
  {                                                                             \
    float avA = __int_as_float(eA.y), avB = __int_as_float(eB.y);               \
    float avC = __int_as_float(eC.y), avD = __int_as_float(eD.y);               \
    float avE = __int_as_float(eE.y), avF = __int_as_float(eF.y);               \
    float avG = __int_as_float(eG.y), avH = __int_as_float(eH.y);               \
    float lA0,lA1,pA, lB0,lB1,pB, lC0,lC1,pC, lD0,lD1,pD;                       \
    float lE0,lE1,pE, lF0,lF1,pF, lG0,lG1,pG, lH0,lH1,pH;                       \
    C1_EDGE2(xA, avA, lA0,lA1, pA);                                             \
    C1_EDGE2(xB, avB, lB0,lB1, pB);                                             \
    C1_EDGE2(xC, avC, lC0,lC1, pC);                                             \
    C1_EDGE2(xD, avD, lD0,lD1, pD);                                             \
    C1_EDGE2(xE, avE, lE0,lE1, pE);                                             \
    C1_EDGE2(xF, avF, lF0,lF1, pF);                                             \
    C1_EDGE2(xG, avG, lG0,lG1, pG);                                             \
    C1_EDGE2(xH, avH, lH0,lH1, pH);                                             \
    float sAB = b1 ? pA : pB, kAB = b1 ? pB : pA;                               \
    float qAB = kAB + __shfl_xor(sAB, 1);                                       \
    float sCD = b1 ? pC : pD, kCD = b1 ? pD : pC;                               \
    float qCD = kCD + __shfl_xor(sCD, 1);                                       \
    float sEF = b1 ? pE : pF, kEF = b1 ? pF : pE;                               \
    float qEF = kEF + __shfl_xor(sEF, 1);                                       \
    float sGH = b1 ? pG : pH, kGH = b1 ? pH : pG;                               \
    float qGH = kGH + __shfl_xor(sGH, 1);                                       \
    float u0s = b2 ? qAB : qCD, u0k = b2 ? qCD : qAB;                           \
    float u0 = u0k + __shfl_xor(u0s, 2);                                        \
    float u1s = b2 ? qEF : qGH, u1k = b2 ? qGH : qEF;                           \
    float u1 = u1k + __shfl_xor(u1s, 2);                                        \
    float vvs = b4 ? u0 : u1, vvk = b4 ? u1 : u0;                               \
    float vv = vvk + __shfl_xor(vvs, 4);                                        \
    vv += __shfl_xor(vv, 8);                                                    \
    vv += __shfl_xor(vv, 16);                                                   \
    float exv = expf(vv);                                                       \
    float xAe = __shfl(exv, 0, 32), xBe = __shfl(exv, 1, 32);                   \
    float xCe = __shfl(exv, 2, 32), xDe = __shfl(exv, 3, 32);                   \
    float xEe = __shfl(exv, 4, 32), xFe = __shfl(exv, 5, 32);                   \
    float xGe = __shfl(exv, 6, 32), xHe = __shfl(exv, 7, 32);                   \
    D += ((xAe + xBe) + (xCe + xDe)) + ((xEe + xFe) + (xGe + xHe));             \
    a0 = fmaf(xDe, lD0, fmaf(xCe, lC0, fmaf(xBe, lB0, fmaf(xAe, lA0, a0))));    \
    a0 = fmaf(xHe, lH0, fmaf(xGe, lG0, fmaf(xFe, lF0, fmaf(xEe, lE0, a0))));    \
    a1 = fmaf(xDe, lD1, fmaf(xCe, lC1, fmaf(xBe, lB1, fmaf(xAe, lA1, a1))));    \
    a1 = fmaf(xHe, lH1, fmaf(xGe, lG1, fmaf(xFe, lF1, fmaf(xEe, lE1, a1))));    \
  }

__global__ void __launch_bounds__(128) k_conv1(
    const float* __restrict__ x,
    const float* __restrict__ Wl, const float* __restrict__ bl,
    const float* __restrict__ Wr, const float* __restrict__ br,
    const float* __restrict__ We, const float* __restrict__ att,
    const int* __restrict__ offs, const int2* __restrict__ cpk,
    const float* __restrict__ bias, const float* __restrict__ g,
    const float* __restrict__ be, unsigned* __restrict__ h1u) {
  __shared__ float lnA[2], lnB[2];
  int t = threadIdx.x;
  int w = t >> 6, l = t & 63;
  int n = blockIdx.x;
  int c = w*128 + 2*l;
  bool b1 = (l & 1) != 0, b2 = (l & 2) != 0, b4 = (l & 4) != 0;

  float2 wl0 = *(const float2*)&Wl[0*HID + c];
  float2 wl1 = *(const float2*)&Wl[1*HID + c];
  float2 wl2 = *(const float2*)&Wl[2*HID + c];
  float2 wl3 = *(const float2*)&Wl[3*HID + c];
  float2 blv = *(const float2*)&bl[c];
  float2 we2 = *(const float2*)&We[c];
  float2 at2 = *(const float2*)&att[c];

  float4 xn = *(const float4*)&x[n*4];
  float r40, r41;
  {
    float2 wr0 = *(const float2*)&Wr[0*HID + c];
    float2 wr1 = *(const float2*)&Wr[1*HID + c];
    float2 wr2 = *(const float2*)&Wr[2*HID + c];
    float2 wr3 = *(const float2*)&Wr[3*HID + c];
    float2 brv = *(const float2*)&br[c];
    r40 = fmaf(xn.x,wr0.x, fmaf(xn.y,wr1.x, fmaf(xn.z,wr2.x, fmaf(xn.w,wr3.x, brv.x))));
    r41 = fmaf(xn.x,wr0.y, fmaf(xn.y,wr1.y, fmaf(xn.z,wr2.y, fmaf(xn.w,wr3.y, brv.y))));
  }

  int js = __builtin_amdgcn_readfirstlane(offs[n]);
  int je = __builtin_amdgcn_readfirstlane(offs[n+1]);

  float D = 0.f, a0 = 0.f, a1 = 0.f;

  int j = js;
  if (je - js >= 16) {
    int2 eA = cpk[j],   eB = cpk[j+1], eC = cpk[j+2], eD = cpk[j+3];
    int2 eE = cpk[j+4], eF = cpk[j+5], eG = cpk[j+6], eH = cpk[j+7];
    int2 fA = cpk[j+8],  fB = cpk[j+9],  fC = cpk[j+10], fD = cpk[j+11];
    int2 fE = cpk[j+12], fF = cpk[j+13], fG = cpk[j+14], fH = cpk[j+15];
    float4 xA = *(const float4*)&x[eA.x*4];
    float4 xB = *(const float4*)&x[eB.x*4];
    float4 xC = *(const float4*)&x[eC.x*4];
    float4 xD = *(const float4*)&x[eD.x*4];
    float4 xE = *(const float4*)&x[eE.x*4];
    float4 xF = *(const float4*)&x[eF.x*4];
    float4 xG = *(const float4*)&x[eG.x*4];
    float4 xH = *(const float4*)&x[eH.x*4];
    for (; j + 15 < je; j += 8) {
      float4 yA = *(const float4*)&x[fA.x*4];
      float4 yB = *(const float4*)&x[fB.x*4];
      float4 yC = *(const float4*)&x[fC.x*4];
      float4 yD = *(const float4*)&x[fD.x*4];
      float4 yE = *(const float4*)&x[fE.x*4];
      float4 yF = *(const float4*)&x[fF.x*4];
      float4 yG = *(const float4*)&x[fG.x*4];
      float4 yH = *(const float4*)&x[fH.x*4];
      int2 gA = cpk[j+16], gB = cpk[j+17], gC = cpk[j+18], gD = cpk[j+19];
      int2 gE = cpk[j+20], gF = cpk[j+21], gG = cpk[j+22], gH = cpk[j+23];
      C1_BODY8();
      eA = fA; eB = fB; eC = fC; eD = fD; eE = fE; eF = fF; eG = fG; eH = fH;
      fA = gA; fB = gB; fC = gC; fD = gD; fE = gE; fF = gF; fG = gG; fH = gH;
      xA = yA; xB = yB; xC = yC; xD = yD; xE = yE; xF = yF; xG = yG; xH = yH;
    }
    C1_BODY8();
    j += 8;
  }
  for (; j + 7 < je; j += 8) {
    int2 eA = cpk[j],   eB = cpk[j+1], eC = cpk[j+2], eD = cpk[j+3];
    int2 eE = cpk[j+4], eF = cpk[j+5], eG = cpk[j+6], eH = cpk[j+7];
    float4 xA = *(const float4*)&x[eA.x*4];
    float4 xB = *(const float4*)&x[eB.x*4];
    float4 xC = *(const float4*)&x[eC.x*4];
    float4 xD = *(const float4*)&x[eD.x*4];
    float4 xE = *(const float4*)&x[eE.x*4];
    float4 xF = *(const float4*)&x[eF.x*4];
    float4 xG = *(const float4*)&x[eG.x*4];
    float4 xH = *(const float4*)&x[eH.x*4];
    C1_BODY8();
  }
  for (; j < je; j++) {
    int2 eA = cpk[j];
    float4 xA = *(const float4*)&x[eA.x*4];
    float avA = __int_as_float(eA.y);
    float lA0,lA1,pA;
    C1_EDGE2(xA, avA, lA0,lA1, pA);
    #pragma unroll
    for (int msk = 1; msk < 32; msk <<= 1) pA += __shfl_xor(pA, msk);
    float eAx = expf(pA);
    D += eAx;
    a0 = fmaf(eAx, lA0, a0);
    a1 = fmaf(eAx, lA1, a1);
  }

  float inv = 1.f / D;
  float2 b2v = *(const float2*)&bias[c];
  float o0 = fmaf(a0, inv, b2v.x);
  float o1 = fmaf(a1, inv, b2v.y);

  // LayerNorm over 256 ch: wave reduce + cross-wave via LDS
  float s = o0 + o1;
  #pragma unroll
  for (int msk = 1; msk < 64; msk <<= 1) s += __shfl_xor(s, msk);
  if (l == 0) lnA[w] = s;
  __syncthreads();
  float mu = (lnA[0] + lnA[1]) * (1.f / 256.f);
  float d0 = o0 - mu, d1 = o1 - mu;
  float sq = d0*d0 + d1*d1;
  #pragma unroll
  for (int msk = 1; msk < 64; msk <<= 1) sq += __shfl_xor(sq, msk);
  if (l == 0) lnB[w] = sq;
  __syncthreads();
  float rstd = rsqrtf((lnB[0] + lnB[1]) * (1.f / 256.f) + 1e-5f);
  float2 g2v  = *(const float2*)&g[c];
  float2 be2v = *(const float2*)&be[c];
  float oy0 = fmaxf(fmaf(d0 * rstd, g2v.x, be2v.x), 0.f);
  float oy1 = fmaxf(fmaf(d1 * rstd, g2v.y, be2v.y), 0.f);
  h1u[n*128 + w*64 + l] = bf16rne(oy0) | (bf16rne(oy1) << 16);
}

// ============================ conv2 =========================================
// 1 node / 128-thread block (2 waves), 2 channels per lane.
// Logit spans 256 ch -> per-batch cross-wave add through double-buffered LDS.
#define C2_EDGE2(x0v, x1v, av, p)                                    \
  {                                                                  \
    float m0 = x0v + fmaf(av, we2.x, r40); m0 = fmaxf(m0, 0.2f*m0);  \
    float m1 = x1v + fmaf(av, we2.y, r41); m1 = fmaxf(m1, 0.2f*m1);  \
    p = m0*at2.x + m1*at2.y;                                         \
  }

#define C2_PROC8()                                                              \
  {                                                                             \
    float xs00 = __uint_as_float(q0 << 16), xs01 = __uint_as_float(q0 & 0xFFFF0000u); \
    float xs10 = __uint_as_float(q1 << 16), xs11 = __uint_as_float(q1 & 0xFFFF0000u); \
    float xs20 = __uint_as_float(q2 << 16), xs21 = __uint_as_float(q2 & 0xFFFF0000u); \
    float xs30 = __uint_as_float(q3 << 16), xs31 = __uint_as_float(q3 & 0xFFFF0000u); \
    float xs40 = __uint_as_float(q4 << 16), xs41 = __uint_as_float(q4 & 0xFFFF0000u); \
    float xs50 = __uint_as_float(q5 << 16), xs51 = __uint_as_float(q5 & 0xFFFF0000u); \
    float xs60 = __uint_as_float(q6 << 16), xs61 = __uint_as_float(q6 & 0xFFFF0000u); \
    float xs70 = __uint_as_float(q7 << 16), xs71 = __uint_as_float(q7 & 0xFFFF0000u); \
    float av0 = __int_as_float(e0.y), av1 = __int_as_float(e1.y);               \
    float av2 = __int_as_float(e2.y), av3 = __int_as_float(e3.y);               \
    float av4 = __int_as_float(e4.y), av5 = __int_as_float(e5.y);               \
    float av6 = __int_as_float(e6.y), av7 = __int_as_float(e7.y);               \
    float p0,p1,p2,p3,p4,p5,p6,p7;                                              \
    C2_EDGE2(xs00, xs01, av0, p0); C2_EDGE2(xs10, xs11, av1, p1);               \
    C2_EDGE2(xs20, xs21, av2, p2); C2_EDGE2(xs30, xs31, av3, p3);               \
    C2_EDGE2(xs40, xs41, av4, p4); C2_EDGE2(xs50, xs51, av5, p5);               \
    C2_EDGE2(xs60, xs61, av6, p6); C2_EDGE2(xs70, xs71, av7, p7);               \
    float sAB = b1 ? p0 : p1, kAB = b1 ? p1 : p0;                               \
    float qAB = kAB + __shfl_xor(sAB, 1);                                       \
    float sCD = b1 ? p2 : p3, kCD = b1 ? p3 : p2;                               \
    float qCD = kCD + __shfl_xor(sCD, 1);                                       \
    float sEF = b1 ? p4 : p5, kEF = b1 ? p5 : p4;                               \
    float qEF = kEF + __shfl_xor(sEF, 1);                                       \
    float sGH = b1 ? p6 : p7, kGH = b1 ? p7 : p6;                               \
    float qGH = kGH + __shfl_xor(sGH, 1);                                       \
    float u0s = b2 ? qAB : qCD, u0k = b2 ? qCD : qAB;                           \
    float u0 = u0k + __shfl_xor(u0s, 2);                                        \
    float u1s = b2 ? qEF : qGH, u1k = b2 ? qGH : qEF;                           \
    float u1 = u1k + __shfl_xor(u1s, 2);                                        \
    float vvs = b4 ? u0 : u1, vvk = b4 ? u1 : u0;                               \
    float vv = vvk + __shfl_xor(vvs, 4);                                        \
    vv += __shfl_xor(vv, 8);                                                    \
    vv += __shfl_xor(vv, 16);                                                   \
    vv += __shfl_xor(vv, 32);                                                   \
    if (l < 8) xch[par][w][l] = vv;                                             \
    __syncthreads();                                                            \
    float vvt = vv + xch[par][1 - w][l & 7];                                    \
    par ^= 1;                                                                   \
    float exv = expf(vvt);                                                      \
    float x0 = __shfl(exv, 0), x1 = __shfl(exv, 1);                             \
    float x2 = __shfl(exv, 2), x3 = __shfl(exv, 3);                             \
    float x4 = __shfl(exv, 4), x5 = __shfl(exv, 5);                             \
    float x6 = __shfl(exv, 6), x7 = __shfl(exv, 7);                             \
    D += ((x0 + x1) + (x2 + x3)) + ((x4 + x5) + (x6 + x7));                     \
    a0 = fmaf(x3, xs30, fmaf(x2, xs20, fmaf(x1, xs10, fmaf(x0, xs00, a0))));    \
    a0 = fmaf(x7, xs70, fmaf(x6, xs60, fmaf(x5, xs50, fmaf(x4, xs40, a0))));    \
    a1 = fmaf(x3, xs31, fmaf(x2, xs21, fmaf(x1, xs11, fmaf(x0, xs01, a1))));    \
    a1 = fmaf(x7, xs71, fmaf(x6, xs61, fmaf(x5, xs51, fmaf(x4, xs41, a1))));    \
  }

__global__ void __launch_bounds__(128) k_conv2(
    const unsigned* __restrict__ xlu, const unsigned* __restrict__ xru,
    const int* __restrict__ offs, const int2* __restrict__ cpk,
    const float* __restrict__ We, const float* __restrict__ att,
    const float* __restrict__ bias, const float* __restrict__ g,
    const float* __restrict__ be, unsigned* __restrict__ h2u) {
  __shared__ float xch[2][2][8];
  __shared__ float lnA[2], lnB[2];
  int t = threadIdx.x;
  int w = t >> 6, l = t & 63;
  int n = blockIdx.x;
  int c = w*128 + 2*l;
  bool b1 = (l & 1) != 0, b2 = (l & 2) != 0, b4 = (l & 4) != 0;
  int par = 0;

  unsigned rq = xru[n*128 + w*64 + l];
  float r40 = __uint_as_float(rq << 16);
  float r41 = __uint_as_float(rq & 0xFFFF0000u);
  float2 we2 = *(const float2*)&We[c];
  float2 at2 = *(const float2*)&att[c];
  int js = __builtin_amdgcn_readfirstlane(offs[n]);
  int je = __builtin_amdgcn_readfirstlane(offs[n+1]);

  float D = 0.f, a0 = 0.f, a1 = 0.f;
  int rowoff = w*64 + l;

  int j = js;
  if (je - js >= 16) {
    int2 e0 = cpk[j],   e1 = cpk[j+1], e2 = cpk[j+2], e3 = cpk[j+3];
    int2 e4 = cpk[j+4], e5 = cpk[j+5], e6 = cpk[j+6], e7 = cpk[j+7];
    int2 f0 = cpk[j+8],  f1 = cpk[j+9],  f2 = cpk[j+10], f3 = cpk[j+11];
    int2 f4 = cpk[j+12], f5 = cpk[j+13], f6 = cpk[j+14], f7 = cpk[j+15];
    unsigned q0 = xlu[e0.x*128 + rowoff];
    unsigned q1 = xlu[e1.x*128 + rowoff];
    unsigned q2 = xlu[e2.x*128 + rowoff];
    unsigned q3 = xlu[e3.x*128 + rowoff];
    unsigned q4 = xlu[e4.x*128 + rowoff];
    unsigned q5 = xlu[e5.x*128 + rowoff];
    unsigned q6 = xlu[e6.x*128 + rowoff];
    unsigned q7 = xlu[e7.x*128 + rowoff];
    for (; j + 15 < je; j += 8) {
      unsigned r0 = xlu[f0.x*128 + rowoff];
      unsigned r1 = xlu[f1.x*128 + rowoff];
      unsigned r2 = xlu[f2.x*128 + rowoff];
      unsigned r3 = xlu[f3.x*128 + rowoff];
      unsigned r4_ = xlu[f4.x*128 + rowoff];
      unsigned r5 = xlu[f5.x*128 + rowoff];
      unsigned r6 = xlu[f6.x*128 + rowoff];
      unsigned r7 = xlu[f7.x*128 + rowoff];
      int2 g0 = cpk[j+16], g1 = cpk[j+17], g2 = cpk[j+18], g3 = cpk[j+19];
      int2 g4 = cpk[j+20], g5 = cpk[j+21], g6 = cpk[j+22], g7 = cpk[j+23];
      C2_PROC8();
      e0 = f0; e1 = f1; e2 = f2; e3 = f3; e4 = f4; e5 = f5; e6 = f6; e7 = f7;
      f0 = g0; f1 = g1; f2 = g2; f3 = g3; f4 = g4; f5 = g5; f6 = g6; f7 = g7;
      q0 = r0; q1 = r1; q2 = r2; q3 = r3; q4 = r4_; q5 = r5; q6 = r6; q7 = r7;
    }
    C2_PROC8();
    j += 8;
  }
  for (; j + 7 < je; j += 8) {
    int2 e0 = cpk[j],   e1 = cpk[j+1], e2 = cpk[j+2], e3 = cpk[j+3];
    int2 e4 = cpk[j+4], e5 = cpk[j+5], e6 = cpk[j+6], e7 = cpk[j+7];
    unsigned q0 = xlu[e0.x*128 + rowoff];
    unsigned q1 = xlu[e1.x*128 + rowoff];
    unsigned q2 = xlu[e2.x*128 + rowoff];
    unsigned q3 = xlu[e3.x*128 + rowoff];
    unsigned q4 = xlu[e4.x*128 + rowoff];
    unsigned q5 = xlu[e5.x*128 + rowoff];
    unsigned q6 = xlu[e6.x*128 + rowoff];
    unsigned q7 = xlu[e7.x*128 + rowoff];
    C2_PROC8();
  }
  for (; j < je; j++) {
    int2 e0 = cpk[j];
    float av0 = __int_as_float(e0.y);
    unsigned q0 = xlu[e0.x*128 + rowoff];
    float xs00 = __uint_as_float(q0 << 16);
    float xs01 = __uint_as_float(q0 & 0xFFFF0000u);
    float p0;
    C2_EDGE2(xs00, xs01, av0, p0);
    #pragma unroll
    for (int msk = 1; msk < 64; msk <<= 1) p0 += __shfl_xor(p0, msk);
    if (l == 0) xch[par][w][0] = p0;
    __syncthreads();
    float pt = p0 + xch[par][1 - w][0];
    par ^= 1;
    float x0 = expf(pt);
    D += x0;
    a0 = fmaf(x0, xs00, a0);
    a1 = fmaf(x0, xs01, a1);
  }

  float inv = 1.f / D;
  float2 b2v = *(const float2*)&bias[c];
  float o0 = fmaf(a0, inv, b2v.x);
  float o1 = fmaf(a1, inv, b2v.y);

  float s = o0 + o1;
  #pragma unroll
  for (int msk = 1; msk < 64; msk <<= 1) s += __shfl_xor(s, msk);
  if (l == 0) lnA[w] = s;
  __syncthreads();
  float mu = (lnA[0] + lnA[1]) * (1.f / 256.f);
  float d0 = o0 - mu, d1 = o1 - mu;
  float sq = d0*d0 + d1*d1;
  #pragma unroll
  for (int msk = 1; msk < 64; msk <<= 1) sq += __shfl_xor(sq, msk);
  if (l == 0) lnB[w] = sq;
  __syncthreads();
  float rstd = rsqrtf((lnB[0] + lnB[1]) * (1.f / 256.f) + 1e-5f);
  float2 g2v  = *(const float2*)&g[c];
  float2 be2v = *(const float2*)&be[c];
  float oy0 = fmaxf(fmaf(d0 * rstd, g2v.x, be2v.x), 0.f);
  float oy1 = fmaxf(fmaf(d1 * rstd, g2v.y, be2v.y), 0.f);
  h2u[n*128 + w*64 + l] = bf16rne(oy0) | (bf16rne(oy1) << 16);
}

// ---------------- dual GEMM: bf16 MFMA 32x32x16; O1 and O2 both bf16 --------
__global__ void __launch_bounds__(256) k_gemm_dual(
    const unsigned short* __restrict__ h1b, const unsigned short* __restrict__ Wt,
    const float* __restrict__ b1, const float* __restrict__ b2,
    unsigned short* __restrict__ O1b, unsigned short* __restrict__ O2b) {
  __shared__ unsigned short A_lds[64][72];
  __shared__ unsigned short W_lds[128][72];
  int t = threadIdx.x;
  int r0 = blockIdx.x * 64;
  int nb0 = blockIdx.y * 128;
  int l = t & 63;
  int wave = t >> 6;
  int wr = wave >> 1, wc = wave & 1;

  floatx16 acc[2] = {{0}, {0}};

  int sar = t >> 2, sak = (t & 3) * 16;
  int arow = min(r0 + sar, N_NODES - 1);
  int swn = t >> 1, swk = (t & 1) * 32;
  const unsigned short* Wrow = &Wt[(nb0 + swn) * 256];

  for (int kb = 0; kb < 256; kb += 64) {
    uint4 av0 = *(const uint4*)&h1b[arow*256 + kb + sak];
    uint4 av1 = *(const uint4*)&h1b[arow*256 + kb + sak + 8];
    uint4 wv0 = *(const uint4*)&Wrow[kb + swk];
    uint4 wv1 = *(const uint4*)&Wrow[kb + swk + 8];
    uint4 wv2 = *(const uint4*)&Wrow[kb + swk + 16];
    uint4 wv3 = *(const uint4*)&Wrow[kb + swk + 24];
    __syncthreads();
    *(uint4*)&A_lds[sar][sak]     = av0;
    *(uint4*)&A_lds[sar][sak + 8] = av1;
    *(uint4*)&W_lds[swn][swk]      = wv0;
    *(uint4*)&W_lds[swn][swk +  8] = wv1;
    *(uint4*)&W_lds[swn][swk + 16] = wv2;
    *(uint4*)&W_lds[swn][swk + 24] = wv3;
    __syncthreads();
    #pragma unroll
    for (int ks = 0; ks < 64; ks += 16) {
      short8 af  = *(const short8*)&A_lds[wr*32 + (l & 31)][ks + 8*(l >> 5)];
      short8 bf0 = *(const short8*)&W_lds[wc*64      + (l & 31)][ks + 8*(l >> 5)];
      short8 bf1 = *(const short8*)&W_lds[wc*64 + 32 + (l & 31)][ks + 8*(l >> 5)];
      acc[0] = __builtin_amdgcn_mfma_f32_32x32x16_bf16(af, bf0, acc[0], 0, 0, 0);
      acc[1] = __builtin_amdgcn_mfma_f32_32x32x16_bf16(af, bf1, acc[1], 0, 0, 0);
    }
  }

  bool isO1 = (nb0 < 256);
  #pragma unroll
  for (int tile = 0; tile < 2; tile++) {
    int col = nb0 + wc*64 + tile*32 + (l & 31);
    float bias = isO1 ? b1[col] : b2[col - 256];
    #pragma unroll
    for (int reg = 0; reg < 16; reg++) {
      int row = (reg & 3) + 8*(reg >> 2) + 4*(l >> 5);
      int r = r0 + wr*32 + row;
      if (r < N_NODES) {
        float v = acc[tile][reg] + bias;
        if (isO1) O1b[r*256 + col] = (unsigned short)bf16rne(v);
        else      O2b[r*256 + (col - 256)] = (unsigned short)bf16rne(v);
      }
    }
  }
}

// ------- policy: bf16 MFMA phase1 (64x128), LDS hid, phase2 + exp -----------
__global__ void __launch_bounds__(256) k_policy(
    const unsigned short* __restrict__ h2b, const unsigned short* __restrict__ Wp1t,
    const float* __restrict__ bp1, const float* __restrict__ Wp2,
    const float* __restrict__ bp2, float* __restrict__ elg, float* __restrict__ tot) {
  __shared__ __align__(16) char smembuf[64 * 132 * 4];   // 33792 B union
  unsigned short* A_lds = (unsigned short*)smembuf;                  // [64][72]
  unsigned short* W_lds = (unsigned short*)(smembuf + 64*72*2);      // [128][72]
  float* hidl = (float*)smembuf;                                     // [64][132]
  __shared__ float wred[4];
  int t = threadIdx.x;
  int r0 = blockIdx.x * 64;
  int l = t & 63;
  int wave = t >> 6;
  int wr = wave >> 1, wc = wave & 1;

  floatx16 acc[2] = {{0}, {0}};

  int sar = t >> 2, sak = (t & 3) * 16;
  int arow = min(r0 + sar, N_NODES - 1);
  int swn = t >> 1, swk = (t & 1) * 32;
  const unsigned short* Wrow = &Wp1t[swn * 256];

  for (int kb = 0; kb < 256; kb += 64) {
    uint4 av0 = *(const uint4*)&h2b[arow*256 + kb + sak];
    uint4 av1 = *(const uint4*)&h2b[arow*256 + kb + sak + 8];
    uint4 wv0 = *(const uint4*)&Wrow[kb + swk];
    uint4 wv1 = *(const uint4*)&Wrow[kb + swk + 8];
    uint4 wv2 = *(const uint4*)&Wrow[kb + swk + 16];
    uint4 wv3 = *(const uint4*)&Wrow[kb + swk + 24];
    __syncthreads();
    *(uint4*)&A_lds[sar*72 + sak]     = av0;
    *(uint4*)&A_lds[sar*72 + sak + 8] = av1;
    *(uint4*)&W_lds[swn*72 + swk]      = wv0;
    *(uint4*)&W_lds[swn*72 + swk +  8] = wv1;
    *(uint4*)&W_lds[swn*72 + swk + 16] = wv2;
    *(uint4*)&W_lds[swn*72 + swk + 24] = wv3;
    __syncthreads();
    #pragma unroll
    for (int ks = 0; ks < 64; ks += 16) {
      short8 af  = *(const short8*)&A_lds[(wr*32 + (l & 31))*72 + ks + 8*(l >> 5)];
      short8 bf0 = *(const short8*)&W_lds[(wc*64      + (l & 31))*72 + ks + 8*(l >> 5)];
      short8 bf1 = *(const short8*)&W_lds[(wc*64 + 32 + (l & 31))*72 + ks + 8*(l >> 5)];
      acc[0] = __builtin_amdgcn_mfma_f32_32x32x16_bf16(af, bf0, acc[0], 0, 0, 0);
      acc[1] = __builtin_amdgcn_mfma_f32_32x32x16_bf16(af, bf1, acc[1], 0, 0, 0);
    }
  }
  __syncthreads();   // A/W dead; smem becomes hidl[64][132]
  #pragma unroll
  for (int tile = 0; tile < 2; tile++) {
    int col = wc*64 + tile*32 + (l & 31);
    float bias = bp1[col];
    #pragma unroll
    for (int reg = 0; reg < 16; reg++) {
      int row = (reg & 3) + 8*(reg >> 2) + 4*(l >> 5) + wr*32;
      hidl[row*132 + col] = fmaxf(acc[tile][reg] + bias, 0.f);
    }
  }
  __syncthreads();
  int nl = t >> 2, i = t & 3;
  float s = bp2[i];
  for (int k = 0; k < 128; k += 4) {
    float4 hv = *(const float4*)&hidl[nl*132 + k];
    s = fmaf(hv.x, Wp2[(k+0)*4 + i],
        fmaf(hv.y, Wp2[(k+1)*4 + i],
        fmaf(hv.z, Wp2[(k+2)*4 + i],
        fmaf(hv.w, Wp2[(k+3)*4 + i], s))));
  }
  int n = r0 + nl;
  float esum = 0.f;
  if (n < N_NODES) {
    float e = expf(s);
    elg[n*4 + i] = e;
    esum = e;
  }
  #pragma unroll
  for (int msk = 1; msk < 64; msk <<= 1) esum += __shfl_xor(esum, msk);
  if ((t & 63) == 0) wred[t >> 6] = esum;
  __syncthreads();
  if (t == 0) atomicAdd(tot, (wred[0] + wred[1]) + (wred[2] + wred[3]));
}

// ---------------- normalize: out = elg * (1/tot) ----------------------------
__global__ void __launch_bounds__(1024) k_sm_final(const float* __restrict__ elg,
                                                   const float* __restrict__ tot,
                                                   float* __restrict__ out) {
  int i = blockIdx.x * 1024 + threadIdx.x;
  float inv = 1.f / tot[0];
  if (i < N_NODES * 4) out[i] = elg[i] * inv;
}

extern "C" void kernel_launch(void* const* d_in, const int* in_sizes, int n_in,
                              void* d_out, int out_size, void* d_ws, size_t ws_size,
                              hipStream_t stream) {
  const float* x    = (const float*)d_in[0];
  const int*   ei   = (const int*)  d_in[1];
  const float* ea   = (const float*)d_in[2];
  const float* Wl1  = (const float*)d_in[3];
  const float* bl1  = (const float*)d_in[4];
  const float* Wr1  = (const float*)d_in[5];
  const float* br1  = (const float*)d_in[6];
  const float* We1  = (const float*)d_in[7];
  const float* att1 = (const float*)d_in[8];
  const float* bias1= (const float*)d_in[9];
  const float* g1   = (const float*)d_in[10];
  const float* be1  = (const float*)d_in[11];
  const float* Wl2  = (const float*)d_in[12];
  const float* bl2  = (const float*)d_in[13];
  const float* Wr2  = (const float*)d_in[14];
  const float* br2  = (const float*)d_in[15];
  const float* We2  = (const float*)d_in[16];
  const float* att2 = (const float*)d_in[17];
  const float* bias2= (const float*)d_in[18];
  const float* g2   = (const float*)d_in[19];
  const float* be2  = (const float*)d_in[20];
  const float* Wp1  = (const float*)d_in[21];
  const float* bp1  = (const float*)d_in[22];
  const float* Wp2  = (const float*)d_in[23];
  const float* bp2  = (const float*)d_in[24];
  float* out = (float*)d_out;

  const int* srcp = ei;
  const int* dstp = ei + N_EDGES;

  // workspace layout: [pdeg | tot] zeroed in ONE memset
  unsigned long long* pdeg = (unsigned long long*)d_ws;    // 10240 x 8B
  float* tot   = (float*)(pdeg + 10240);     // 16
  int*   offs  = (int*)(tot + 16);           // 10240
  float* lattr = (float*)(offs + 10240);     // 10240
  int*   rank  = (int*)(lattr + 10240);      // 320192
  int2*  cpk   = (int2*)(rank + 320192);     // CPK_CAP int2 (pad zeroed by scatter)
  unsigned short* h1b   = (unsigned short*)(cpk + CPK_CAP);  // 10000x256 bf16
  unsigned short* h2b   = h1b;               // conv2 output aliases (h1b dead)
  unsigned short* xl2bf = h1b + 2560000;     // 10000x256 bf16
  unsigned short* xr2b  = xl2bf + 2560000;   // 10000x256 bf16
  float* elg   = (float*)(xr2b + 2560000);   // 40960
  unsigned short* Wt   = (unsigned short*)(elg + 40960);   // 512x256 bf16
  unsigned short* Wp1t = Wt + 512*256;                     // 128x256 bf16

  hipMemsetAsync(pdeg, 0, 10240 * 8 + 64, stream);

  k_front  <<<1250 + 192, 256, 0, stream>>>(dstp, ea, pdeg, rank,
                                            Wl2, Wr2, Wp1, Wt, Wp1t);
  k_scan   <<<1, 256, 0, stream>>>(pdeg, offs, lattr);
  k_scatter<<<(CPK_CAP + 255)/256, 256, 0, stream>>>(srcp, dstp, ea, lattr, offs,
                                                     rank, cpk);
  k_conv1  <<<N_NODES, 128, 0, stream>>>(x, Wl1, bl1, Wr1, br1, We1, att1,
                                         offs, cpk, bias1, g1, be1, (unsigned*)h1b);
  k_gemm_dual<<<dim3(157, 4), 256, 0, stream>>>(h1b, Wt, bl2, br2, xl2bf, xr2b);
  k_conv2  <<<N_NODES, 128, 0, stream>>>((const unsigned*)xl2bf, (const unsigned*)xr2b,
                                         offs, cpk, We2, att2, bias2, g2, be2,
                                         (unsigned*)h2b);
  k_policy <<<157, 256, 0, stream>>>(h2b, Wp1t, bp1, Wp2, bp2, elg, tot);
  k_sm_final<<<40, 1024, 0, stream>>>(elg, tot, out);
}

// Round 15
// 251.243 us; speedup vs baseline: 1.0351x; 1.0351x over previous
//
#include <hip/hip_runtime.h>
#include <math.h>

#define N_NODES 10000
#define N_EDGES 320000
#define N_AUG   (N_EDGES + N_NODES)
#define CPK_CAP 330752
#define HID     256

typedef short short8 __attribute__((ext_vector_type(8)));
typedef float floatx16 __attribute__((ext_vector_type(16)));

// bf16 round-to-nearest-even, as the low 16 bits of a uint
static __device__ __forceinline__ unsigned bf16rne(float f) {
  unsigned u = __float_as_uint(f);
  return (u + 0x7FFFu + ((u >> 16) & 1u)) >> 16;
}

// ------- fused front kernel ------------------------------------------------
// blocks [0,1250): degree+rank+attr-sum via ONE packed 64-bit atomic per edge
//   (count in high word; attr as biased fixed-point 2^-18 in low word)
// blocks [1250,1442): weight conversion (W1|W2 -> Wt bf16 T, Wp1 -> Wp1t)
__global__ void __launch_bounds__(256) k_front(
    const int* __restrict__ dst, const float* __restrict__ ea,
    unsigned long long* __restrict__ pdeg, int* __restrict__ rank,
    const float* __restrict__ W1, const float* __restrict__ W2,
    const float* __restrict__ Wp1,
    unsigned short* __restrict__ Wt, unsigned short* __restrict__ Wp1t) {
  __shared__ float tile[32][33];
  int bi = blockIdx.x;
  int t = threadIdx.x;
  if (bi < 1250) {
    int e = bi * 256 + t;
    int d = dst[e];
    int fx = __float2int_rn(ea[e] * 262144.0f);       // 2^18 scale
    unsigned long long pk = 0x100000000ull
                          + (unsigned long long)(unsigned)(fx + 2097152);
    unsigned long long old = atomicAdd(&pdeg[d], pk);
    rank[e] = (int)(old >> 32);
    return;
  }
  int pb = bi - 1250;
  int z = pb >> 6;
  int rem = pb & 63;
  int kb = (rem & 7) * 32, nb = (rem >> 3) * 32;
  int tx = t & 31, ty = t >> 5;
  if (z < 2) {
    const float* W = z ? W2 : W1;
    int rowoff = z * 256;
    #pragma unroll
    for (int rep = 0; rep < 4; rep++)
      tile[ty + 8*rep][tx] = W[(kb + ty + 8*rep)*HID + nb + tx];
    __syncthreads();
    #pragma unroll
    for (int rep = 0; rep < 4; rep++) {
      int n = nb + ty + 8*rep;
      Wt[(rowoff + n)*256 + kb + tx] = (unsigned short)bf16rne(tile[tx][ty + 8*rep]);
    }
  } else {
    if (nb >= 128) return;
    #pragma unroll
    for (int rep = 0; rep < 4; rep++)
      tile[ty + 8*rep][tx] = Wp1[(kb + ty + 8*rep)*128 + nb + tx];
    __syncthreads();
    #pragma unroll
    for (int rep = 0; rep < 4; rep++) {
      int n = nb + ty + 8*rep;
      Wp1t[n*256 + kb + tx] = (unsigned short)bf16rne(tile[tx][ty + 8*rep]);
    }
  }
}

// ------- exclusive scan of (deg+1) over 10000 nodes (parallel), + loop_attr --
__global__ void __launch_bounds__(256) k_scan(
    const unsigned long long* __restrict__ pdeg,
    int* __restrict__ offs, float* __restrict__ lattr) {
  __shared__ int wsum[4];
  int t = threadIdx.x;
  int base = t * 40;
  int s = 0;
  for (int i = 0; i < 40; i++) {
    int n = base + i;
    if (n < N_NODES) s += (int)(pdeg[n] >> 32) + 1;
  }
  int v = s;
  #pragma unroll
  for (int d = 1; d < 64; d <<= 1) {
    int u = __shfl_up(v, d);
    if ((t & 63) >= d) v += u;
  }
  if ((t & 63) == 63) wsum[t >> 6] = v;
  __syncthreads();
  int wb = 0;
  for (int i = 0; i < (t >> 6); i++) wb += wsum[i];
  int run = wb + v - s;
  for (int i = 0; i < 40; i++) {
    int n = base + i;
    if (n < N_NODES) {
      offs[n] = run;
      unsigned long long pv = pdeg[n];
      int d = (int)(pv >> 32);
      run += d + 1;
      int lower = (int)(pv & 0xFFFFFFFFull);
      float asum = (float)(lower - d * 2097152) * (1.f / 262144.f);
      lattr[n] = asum / (float)max(d, 1);
    }
  }
  if (t == 255) offs[N_NODES] = wb + v;
}

// ------- scatter edges into CSR by dst (atomic-free via rank); zero pad -----
__global__ void k_scatter(const int* __restrict__ src, const int* __restrict__ dst,
                          const float* __restrict__ ea, const float* __restrict__ lattr,
                          const int* __restrict__ offs, const int* __restrict__ rank,
                          int2* __restrict__ cpk) {
  int e = blockIdx.x * blockDim.x + threadIdx.x;
  if (e >= N_AUG) {
    if (e < CPK_CAP) cpk[e] = make_int2(0, 0);   // pad: row-0, av=0
    return;
  }
  int pos, s; float a;
  if (e < N_EDGES) {
    s = src[e];
    int d = dst[e];
    a = ea[e];
    pos = offs[d] + rank[e];
  } else {
    s = e - N_EDGES;
    a = lattr[s];
    pos = offs[s + 1] - 1;    // self-loop last in segment
  }
  cpk[pos] = make_int2(s, __float_as_int(a));
}

// ============================ conv1 =========================================
#define C1_EDGE(xs, av, l0, l1, l2, l3, p)                                              \
  {                                                                                     \
    l0 = fmaf(xs.x,wl0.x, fmaf(xs.y,wl1.x, fmaf(xs.z,wl2.x, fmaf(xs.w,wl3.x, blv.x)))); \
    l1 = fmaf(xs.x,wl0.y, fmaf(xs.y,wl1.y, fmaf(xs.z,wl2.y, fmaf(xs.w,wl3.y, blv.y)))); \
    l2 = fmaf(xs.x,wl0.z, fmaf(xs.y,wl1.z, fmaf(xs.z,wl2.z, fmaf(xs.w,wl3.z, blv.z)))); \
    l3 = fmaf(xs.x,wl0.w, fmaf(xs.y,wl1.w, fmaf(xs.z,wl2.w, fmaf(xs.w,wl3.w, blv.w)))); \
    float m0 = l0 + fmaf(av, we.x, r4.x); m0 = fmaxf(m0, 0.2f*m0);                      \
    float m1 = l1 + fmaf(av, we.y, r4.y); m1 = fmaxf(m1, 0.2f*m1);                      \
    float m2 = l2 + fmaf(av, we.z, r4.z); m2 = fmaxf(m2, 0.2f*m2);                      \
    float m3 = l3 + fmaf(av, we.w, r4.w); m3 = fmaxf(m3, 0.2f*m3);                      \
    p = m0*at.x + m1*at.y + m2*at.z + m3*at.w;                                          \
  }

#define C1_BODY8()                                                              \
  {                                                                             \
    float avA = __int_as_float(eA.y), avB = __int_as_float(eB.y);               \
    float avC = __int_as_float(eC.y), avD = __int_as_float(eD.y);               \
    float avE = __int_as_float(eE.y), avF = __int_as_float(eF.y);               \
    float avG = __int_as_float(eG.y), avH = __int_as_float(eH.y);               \
    float lA0,lA1,lA2,lA3,pA, lB0,lB1,lB2,lB3,pB;                               \
    float lC0,lC1,lC2,lC3,pC, lD0,lD1,lD2,lD3,pD;                               \
    float lE0,lE1,lE2,lE3,pE, lF0,lF1,lF2,lF3,pF;                               \
    float lG0,lG1,lG2,lG3,pG, lH0,lH1,lH2,lH3,pH;                               \
    C1_EDGE(xA, avA, lA0,lA1,lA2,lA3, pA);                                      \
    C1_EDGE(xB, avB, lB0,lB1,lB2,lB3, pB);                                      \
    C1_EDGE(xC, avC, lC0,lC1,lC2,lC3, pC);                                      \
    C1_EDGE(xD, avD, lD0,lD1,lD2,lD3, pD);                                      \
    C1_EDGE(xE, avE, lE0,lE1,lE2,lE3, pE);                                      \
    C1_EDGE(xF, avF, lF0,lF1,lF2,lF3, pF);                                      \
    C1_EDGE(xG, avG, lG0,lG1,lG2,lG3, pG);                                      \
    C1_EDGE(xH, avH, lH0,lH1,lH2,lH3, pH);                                      \
    float sAB = b1 ? pA : pB, kAB = b1 ? pB : pA;                               \
    float qAB = kAB + __shfl_xor(sAB, 1);                                       \
    float sCD = b1 ? pC : pD, kCD = b1 ? pD : pC;                               \
    float qCD = kCD + __shfl_xor(sCD, 1);                                       \
    float sEF = b1 ? pE : pF, kEF = b1 ? pF : pE;                               \
    float qEF = kEF + __shfl_xor(sEF, 1);                                       \
    float sGH = b1 ? pG : pH, kGH = b1 ? pH : pG;                               \
    float qGH = kGH + __shfl_xor(sGH, 1);                                       \
    float u0s = b2 ? qAB : qCD, u0k = b2 ? qCD : qAB;                           \
    float u0 = u0k + __shfl_xor(u0s, 2);                                        \
    float u1s = b2 ? qEF : qGH, u1k = b2 ? qGH : qEF;                           \
    float u1 = u1k + __shfl_xor(u1s, 2);                                        \
    float vvs = b4 ? u0 : u1, vvk = b4 ? u1 : u0;                               \
    float vv = vvk + __shfl_xor(vvs, 4);                                        \
    vv += __shfl_xor(vv, 8);                                                    \
    float exv = expf(vv);                                                       \
    float xAe = __shfl(exv, 0, 16), xBe = __shfl(exv, 1, 16);                   \
    float xCe = __shfl(exv, 2, 16), xDe = __shfl(exv, 3, 16);                   \
    float xEe = __shfl(exv, 4, 16), xFe = __shfl(exv, 5, 16);                   \
    float xGe = __shfl(exv, 6, 16), xHe = __shfl(exv, 7, 16);                   \
    D += ((xAe + xBe) + (xCe + xDe)) + ((xEe + xFe) + (xGe + xHe));             \
    a0 = fmaf(xDe, lD0, fmaf(xCe, lC0, fmaf(xBe, lB0, fmaf(xAe, lA0, a0))));    \
    a0 = fmaf(xHe, lH0, fmaf(xGe, lG0, fmaf(xFe, lF0, fmaf(xEe, lE0, a0))));    \
    a1 = fmaf(xDe, lD1, fmaf(xCe, lC1, fmaf(xBe, lB1, fmaf(xAe, lA1, a1))));    \
    a1 = fmaf(xHe, lH1, fmaf(xGe, lG1, fmaf(xFe, lF1, fmaf(xEe, lE1, a1))));    \
    a2 = fmaf(xDe, lD2, fmaf(xCe, lC2, fmaf(xBe, lB2, fmaf(xAe, lA2, a2))));    \
    a2 = fmaf(xHe, lH2, fmaf(xGe, lG2, fmaf(xFe, lF2, fmaf(xEe, lE2, a2))));    \
    a3 = fmaf(xDe, lD3, fmaf(xCe, lC3, fmaf(xBe, lB3, fmaf(xAe, lA3, a3))));    \
    a3 = fmaf(xHe, lH3, fmaf(xGe, lG3, fmaf(xFe, lF3, fmaf(xEe, lE3, a3))));    \
  }

__global__ void __launch_bounds__(256) k_conv1(
    const float* __restrict__ x,
    const float* __restrict__ Wl, const float* __restrict__ bl,
    const float* __restrict__ Wr, const float* __restrict__ br,
    const float* __restrict__ We, const float* __restrict__ att,
    const int* __restrict__ offs, const int2* __restrict__ cpk,
    const float* __restrict__ bias, const float* __restrict__ g,
    const float* __restrict__ be, uint2* __restrict__ h1b) {
  int t = threadIdx.x;
  int n = blockIdx.x * 4 + (t >> 6);
  int c = 4 * (t & 63);
  bool b1 = (t & 1) != 0, b2 = (t & 2) != 0, b4 = (t & 4) != 0;

  float4 wl0 = *(const float4*)&Wl[0*HID + c];
  float4 wl1 = *(const float4*)&Wl[1*HID + c];
  float4 wl2 = *(const float4*)&Wl[2*HID + c];
  float4 wl3 = *(const float4*)&Wl[3*HID + c];
  float4 blv = *(const float4*)&bl[c];
  float4 we  = *(const float4*)&We[c];
  float4 at  = *(const float4*)&att[c];

  float4 xn = *(const float4*)&x[n*4];
  float4 r4;
  {
    float4 wr0 = *(const float4*)&Wr[0*HID + c];
    float4 wr1 = *(const float4*)&Wr[1*HID + c];
    float4 wr2 = *(const float4*)&Wr[2*HID + c];
    float4 wr3 = *(const float4*)&Wr[3*HID + c];
    float4 brv = *(const float4*)&br[c];
    r4.x = fmaf(xn.x,wr0.x, fmaf(xn.y,wr1.x, fmaf(xn.z,wr2.x, fmaf(xn.w,wr3.x, brv.x))));
    r4.y = fmaf(xn.x,wr0.y, fmaf(xn.y,wr1.y, fmaf(xn.z,wr2.y, fmaf(xn.w,wr3.y, brv.y))));
    r4.z = fmaf(xn.x,wr0.z, fmaf(xn.y,wr1.z, fmaf(xn.z,wr2.z, fmaf(xn.w,wr3.z, brv.z))));
    r4.w = fmaf(xn.x,wr0.w, fmaf(xn.y,wr1.w, fmaf(xn.z,wr2.w, fmaf(xn.w,wr3.w, brv.w))));
  }

  int js = __builtin_amdgcn_readfirstlane(offs[n]);
  int je = __builtin_amdgcn_readfirstlane(offs[n+1]);

  float D = 0.f, a0 = 0.f, a1 = 0.f, a2 = 0.f, a3 = 0.f;

  int j = js;
  if (je - js >= 16) {
    int2 eA = cpk[j],   eB = cpk[j+1], eC = cpk[j+2], eD = cpk[j+3];
    int2 eE = cpk[j+4], eF = cpk[j+5], eG = cpk[j+6], eH = cpk[j+7];
    int2 fA = cpk[j+8],  fB = cpk[j+9],  fC = cpk[j+10], fD = cpk[j+11];
    int2 fE = cpk[j+12], fF = cpk[j+13], fG = cpk[j+14], fH = cpk[j+15];
    float4 xA = *(const float4*)&x[eA.x*4];
    float4 xB = *(const float4*)&x[eB.x*4];
    float4 xC = *(const float4*)&x[eC.x*4];
    float4 xD = *(const float4*)&x[eD.x*4];
    float4 xE = *(const float4*)&x[eE.x*4];
    float4 xF = *(const float4*)&x[eF.x*4];
    float4 xG = *(const float4*)&x[eG.x*4];
    float4 xH = *(const float4*)&x[eH.x*4];
    for (; j + 15 < je; j += 8) {
      float4 yA = *(const float4*)&x[fA.x*4];
      float4 yB = *(const float4*)&x[fB.x*4];
      float4 yC = *(const float4*)&x[fC.x*4];
      float4 yD = *(const float4*)&x[fD.x*4];
      float4 yE = *(const float4*)&x[fE.x*4];
      float4 yF = *(const float4*)&x[fF.x*4];
      float4 yG = *(const float4*)&x[fG.x*4];
      float4 yH = *(const float4*)&x[fH.x*4];
      int2 gA = cpk[j+16], gB = cpk[j+17], gC = cpk[j+18], gD = cpk[j+19];
      int2 gE = cpk[j+20], gF = cpk[j+21], gG = cpk[j+22], gH = cpk[j+23];
      C1_BODY8();
      eA = fA; eB = fB; eC = fC; eD = fD; eE = fE; eF = fF; eG = fG; eH = fH;
      fA = gA; fB = gB; fC = gC; fD = gD; fE = gE; fF = gF; fG = gG; fH = gH;
      xA = yA; xB = yB; xC = yC; xD = yD; xE = yE; xF = yF; xG = yG; xH = yH;
    }
    C1_BODY8();
    j += 8;
  }
  for (; j + 7 < je; j += 8) {
    int2 eA = cpk[j],   eB = cpk[j+1], eC = cpk[j+2], eD = cpk[j+3];
    int2 eE = cpk[j+4], eF = cpk[j+5], eG = cpk[j+6], eH = cpk[j+7];
    float4 xA = *(const float4*)&x[eA.x*4];
    float4 xB = *(const float4*)&x[eB.x*4];
    float4 xC = *(const float4*)&x[eC.x*4];
    float4 xD = *(const float4*)&x[eD.x*4];
    float4 xE = *(const float4*)&x[eE.x*4];
    float4 xF = *(const float4*)&x[eF.x*4];
    float4 xG = *(const float4*)&x[eG.x*4];
    float4 xH = *(const float4*)&x[eH.x*4];
    C1_BODY8();
  }
  for (; j < je; j++) {
    int2 eA = cpk[j];
    float4 xA = *(const float4*)&x[eA.x*4];
    float avA = __int_as_float(eA.y);
    float lA0,lA1,lA2,lA3,pA;
    C1_EDGE(xA, avA, lA0,lA1,lA2,lA3, pA);
    #pragma unroll
    for (int msk = 1; msk < 16; msk <<= 1) pA += __shfl_xor(pA, msk);
    float eAx = expf(pA);
    D += eAx;
    a0 = fmaf(eAx, lA0, a0);
    a1 = fmaf(eAx, lA1, a1);
    a2 = fmaf(eAx, lA2, a2);
    a3 = fmaf(eAx, lA3, a3);
  }

  float inv = 1.f / D;
  float4 b4v = *(const float4*)&bias[c];
  float o0 = fmaf(a0, inv, b4v.x);
  float o1 = fmaf(a1, inv, b4v.y);
  float o2 = fmaf(a2, inv, b4v.z);
  float o3 = fmaf(a3, inv, b4v.w);

  float s = o0 + o1 + o2 + o3;
  #pragma unroll
  for (int msk = 1; msk < 64; msk <<= 1) s += __shfl_xor(s, msk);
  float mu = s * (1.f / 256.f);
  float d0 = o0 - mu, d1 = o1 - mu, d2 = o2 - mu, d3 = o3 - mu;
  float sq = d0*d0 + d1*d1 + d2*d2 + d3*d3;
  #pragma unroll
  for (int msk = 1; msk < 64; msk <<= 1) sq += __shfl_xor(sq, msk);
  float rstd = rsqrtf(sq * (1.f / 256.f) + 1e-5f);
  float4 g4  = *(const float4*)&g[c];
  float4 be4 = *(const float4*)&be[c];
  float oy0 = fmaxf(fmaf(d0 * rstd, g4.x, be4.x), 0.f);
  float oy1 = fmaxf(fmaf(d1 * rstd, g4.y, be4.y), 0.f);
  float oy2 = fmaxf(fmaf(d2 * rstd, g4.z, be4.z), 0.f);
  float oy3 = fmaxf(fmaf(d3 * rstd, g4.w, be4.w), 0.f);
  uint2 pk;
  pk.x = bf16rne(oy0) | (bf16rne(oy1) << 16);
  pk.y = bf16rne(oy2) | (bf16rne(oy3) << 16);
  h1b[n*64 + (t & 63)] = pk;
}

// ============================ conv2 =========================================
#define C2_LOAD(q, xs)                                  \
  float4 xs;                                            \
  xs.x = __uint_as_float(q.x << 16);                    \
  xs.y = __uint_as_float(q.x & 0xFFFF0000u);            \
  xs.z = __uint_as_float(q.y << 16);                    \
  xs.w = __uint_as_float(q.y & 0xFFFF0000u);

#define C2_EDGE(xs, av, p)                                           \
  {                                                                  \
    float m0 = xs.x + fmaf(av, we.x, r4.x); m0 = fmaxf(m0, 0.2f*m0); \
    float m1 = xs.y + fmaf(av, we.y, r4.y); m1 = fmaxf(m1, 0.2f*m1); \
    float m2 = xs.z + fmaf(av, we.z, r4.z); m2 = fmaxf(m2, 0.2f*m2); \
    float m3 = xs.w + fmaf(av, we.w, r4.w); m3 = fmaxf(m3, 0.2f*m3); \
    p = m0*at.x + m1*at.y + m2*at.z + m3*at.w;                       \
  }

#define C2_PROC8()                                                              \
  {                                                                             \
    C2_LOAD(q0, xs0); C2_LOAD(q1, xs1); C2_LOAD(q2, xs2); C2_LOAD(q3, xs3);     \
    C2_LOAD(q4, xs4); C2_LOAD(q5, xs5); C2_LOAD(q6, xs6); C2_LOAD(q7, xs7);     \
    float av0 = __int_as_float(e0.y), av1 = __int_as_float(e1.y);               \
    float av2 = __int_as_float(e2.y), av3 = __int_as_float(e3.y);               \
    float av4 = __int_as_float(e4.y), av5 = __int_as_float(e5.y);               \
    float av6 = __int_as_float(e6.y), av7 = __int_as_float(e7.y);               \
    float p0,p1,p2,p3,p4,p5,p6,p7;                                              \
    C2_EDGE(xs0, av0, p0); C2_EDGE(xs1, av1, p1);                               \
    C2_EDGE(xs2, av2, p2); C2_EDGE(xs3, av3, p3);                               \
    C2_EDGE(xs4, av4, p4); C2_EDGE(xs5, av5, p5);                               \
    C2_EDGE(xs6, av6, p6); C2_EDGE(xs7, av7, p7);                               \
    float sAB = b1 ? p0 : p1, kAB = b1 ? p1 : p0;                               \
    float qAB = kAB + __shfl_xor(sAB, 1);                                       \
    float sCD = b1 ? p2 : p3, kCD = b1 ? p3 : p2;                               \
    float qCD = kCD + __shfl_xor(sCD, 1);                                       \
    float sEF = b1 ? p4 : p5, kEF = b1 ? p5 : p4;                               \
    float qEF = kEF + __shfl_xor(sEF, 1);                                       \
    float sGH = b1 ? p6 : p7, kGH = b1 ? p7 : p6;                               \
    float qGH = kGH + __shfl_xor(sGH, 1);                                       \
    float u0s = b2 ? qAB : qCD, u0k = b2 ? qCD : qAB;                           \
    float u0 = u0k + __shfl_xor(u0s, 2);                                        \
    float u1s = b2 ? qEF : qGH, u1k = b2 ? qGH : qEF;                           \
    float u1 = u1k + __shfl_xor(u1s, 2);                                        \
    float vvs = b4 ? u0 : u1, vvk = b4 ? u1 : u0;                               \
    float vv = vvk + __shfl_xor(vvs, 4);                                        \
    vv += __shfl_xor(vv, 8);                                                    \
    vv += __shfl_xor(vv, 16);                                                   \
    vv += __shfl_xor(vv, 32);                                                   \
    float exv = expf(vv);                                                       \
    float x0 = __shfl(exv, 0), x1 = __shfl(exv, 1);                             \
    float x2 = __shfl(exv, 2), x3 = __shfl(exv, 3);                             \
    float x4 = __shfl(exv, 4), x5 = __shfl(exv, 5);                             \
    float x6 = __shfl(exv, 6), x7 = __shfl(exv, 7);                             \
    D += ((x0 + x1) + (x2 + x3)) + ((x4 + x5) + (x6 + x7));                     \
    a0 = fmaf(x3, xs3.x, fmaf(x2, xs2.x, fmaf(x1, xs1.x, fmaf(x0, xs0.x, a0))));\
    a0 = fmaf(x7, xs7.x, fmaf(x6, xs6.x, fmaf(x5, xs5.x, fmaf(x4, xs4.x, a0))));\
    a1 = fmaf(x3, xs3.y, fmaf(x2, xs2.y, fmaf(x1, xs1.y, fmaf(x0, xs0.y, a1))));\
    a1 = fmaf(x7, xs7.y, fmaf(x6, xs6.y, fmaf(x5, xs5.y, fmaf(x4, xs4.y, a1))));\
    a2 = fmaf(x3, xs3.z, fmaf(x2, xs2.z, fmaf(x1, xs1.z, fmaf(x0, xs0.z, a2))));\
    a2 = fmaf(x7, xs7.z, fmaf(x6, xs6.z, fmaf(x5, xs5.z, fmaf(x4, xs4.z, a2))));\
    a3 = fmaf(x3, xs3.w, fmaf(x2, xs2.w, fmaf(x1, xs1.w, fmaf(x0, xs0.w, a3))));\
    a3 = fmaf(x7, xs7.w, fmaf(x6, xs6.w, fmaf(x5, xs5.w, fmaf(x4, xs4.w, a3))));\
  }

__global__ void __launch_bounds__(256) k_conv2(
    const uint2* __restrict__ xlb, const uint2* __restrict__ xrb,
    const int* __restrict__ offs, const int2* __restrict__ cpk,
    const float* __restrict__ We, const float* __restrict__ att,
    const float* __restrict__ bias, const float* __restrict__ g,
    const float* __restrict__ be, uint2* __restrict__ h2b) {
  int t = threadIdx.x;
  int n = blockIdx.x * 4 + (t >> 6);
  int lane = t & 63;
  int c = 4 * lane;
  bool b1 = (t & 1) != 0, b2 = (t & 2) != 0, b4 = (t & 4) != 0;
  uint2 rq = xrb[n*64 + lane];
  C2_LOAD(rq, r4);
  float4 we = *(const float4*)&We[c];
  float4 at = *(const float4*)&att[c];
  int js = __builtin_amdgcn_readfirstlane(offs[n]);
  int je = __builtin_amdgcn_readfirstlane(offs[n+1]);

  float D = 0.f, a0 = 0.f, a1 = 0.f, a2 = 0.f, a3 = 0.f;

  int j = js;
  if (je - js >= 16) {
    int2 e0 = cpk[j],   e1 = cpk[j+1], e2 = cpk[j+2], e3 = cpk[j+3];
    int2 e4 = cpk[j+4], e5 = cpk[j+5], e6 = cpk[j+6], e7 = cpk[j+7];
    int2 f0 = cpk[j+8],  f1 = cpk[j+9],  f2 = cpk[j+10], f3 = cpk[j+11];
    int2 f4 = cpk[j+12], f5 = cpk[j+13], f6 = cpk[j+14], f7 = cpk[j+15];
    uint2 q0 = xlb[e0.x*64 + lane];
    uint2 q1 = xlb[e1.x*64 + lane];
    uint2 q2 = xlb[e2.x*64 + lane];
    uint2 q3 = xlb[e3.x*64 + lane];
    uint2 q4 = xlb[e4.x*64 + lane];
    uint2 q5 = xlb[e5.x*64 + lane];
    uint2 q6 = xlb[e6.x*64 + lane];
    uint2 q7 = xlb[e7.x*64 + lane];
    for (; j + 15 < je; j += 8) {
      uint2 r0 = xlb[f0.x*64 + lane];
      uint2 r1 = xlb[f1.x*64 + lane];
      uint2 r2 = xlb[f2.x*64 + lane];
      uint2 r3 = xlb[f3.x*64 + lane];
      uint2 r4_ = xlb[f4.x*64 + lane];
      uint2 r5 = xlb[f5.x*64 + lane];
      uint2 r6 = xlb[f6.x*64 + lane];
      uint2 r7 = xlb[f7.x*64 + lane];
      int2 g0 = cpk[j+16], g1 = cpk[j+17], g2 = cpk[j+18], g3 = cpk[j+19];
      int2 g4 = cpk[j+20], g5 = cpk[j+21], g6 = cpk[j+22], g7 = cpk[j+23];
      C2_PROC8();
      e0 = f0; e1 = f1; e2 = f2; e3 = f3; e4 = f4; e5 = f5; e6 = f6; e7 = f7;
      f0 = g0; f1 = g1; f2 = g2; f3 = g3; f4 = g4; f5 = g5; f6 = g6; f7 = g7;
      q0 = r0; q1 = r1; q2 = r2; q3 = r3; q4 = r4_; q5 = r5; q6 = r6; q7 = r7;
    }
    C2_PROC8();
    j += 8;
  }
  for (; j + 7 < je; j += 8) {
    int2 e0 = cpk[j],   e1 = cpk[j+1], e2 = cpk[j+2], e3 = cpk[j+3];
    int2 e4 = cpk[j+4], e5 = cpk[j+5], e6 = cpk[j+6], e7 = cpk[j+7];
    uint2 q0 = xlb[e0.x*64 + lane];
    uint2 q1 = xlb[e1.x*64 + lane];
    uint2 q2 = xlb[e2.x*64 + lane];
    uint2 q3 = xlb[e3.x*64 + lane];
    uint2 q4 = xlb[e4.x*64 + lane];
    uint2 q5 = xlb[e5.x*64 + lane];
    uint2 q6 = xlb[e6.x*64 + lane];
    uint2 q7 = xlb[e7.x*64 + lane];
    C2_PROC8();
  }
  for (; j < je; j++) {
    int2 e0 = cpk[j];
    float av0 = __int_as_float(e0.y);
    uint2 q0 = xlb[e0.x*64 + lane];
    C2_LOAD(q0, xs0);
    float p0;
    C2_EDGE(xs0, av0, p0);
    #pragma unroll
    for (int msk = 1; msk < 64; msk <<= 1) p0 += __shfl_xor(p0, msk);
    float x0 = expf(p0);
    D += x0;
    a0 = fmaf(x0, xs0.x, a0);
    a1 = fmaf(x0, xs0.y, a1);
    a2 = fmaf(x0, xs0.z, a2);
    a3 = fmaf(x0, xs0.w, a3);
  }

  float inv = 1.f / D;
  float4 b4v = *(const float4*)&bias[c];
  float o0 = fmaf(a0, inv, b4v.x);
  float o1 = fmaf(a1, inv, b4v.y);
  float o2 = fmaf(a2, inv, b4v.z);
  float o3 = fmaf(a3, inv, b4v.w);

  float s = o0 + o1 + o2 + o3;
  #pragma unroll
  for (int msk = 1; msk < 64; msk <<= 1) s += __shfl_xor(s, msk);
  float mu = s * (1.f / 256.f);
  float d0 = o0 - mu, d1 = o1 - mu, d2 = o2 - mu, d3 = o3 - mu;
  float sq = d0*d0 + d1*d1 + d2*d2 + d3*d3;
  #pragma unroll
  for (int msk = 1; msk < 64; msk <<= 1) sq += __shfl_xor(sq, msk);
  float rstd = rsqrtf(sq * (1.f / 256.f) + 1e-5f);
  float4 g4  = *(const float4*)&g[c];
  float4 be4 = *(const float4*)&be[c];
  float oy0 = fmaxf(fmaf(d0 * rstd, g4.x, be4.x), 0.f);
  float oy1 = fmaxf(fmaf(d1 * rstd, g4.y, be4.y), 0.f);
  float oy2 = fmaxf(fmaf(d2 * rstd, g4.z, be4.z), 0.f);
  float oy3 = fmaxf(fmaf(d3 * rstd, g4.w, be4.w), 0.f);
  uint2 pk;
  pk.x = bf16rne(oy0) | (bf16rne(oy1) << 16);
  pk.y = bf16rne(oy2) | (bf16rne(oy3) << 16);
  h2b[n*64 + lane] = pk;
}

// ---------------- dual GEMM: bf16 MFMA 32x32x16; O1 and O2 both bf16 --------
__global__ void __launch_bounds__(256) k_gemm_dual(
    const unsigned short* __restrict__ h1b, const unsigned short* __restrict__ Wt,
    const float* __restrict__ b1, const float* __restrict__ b2,
    unsigned short* __restrict__ O1b, unsigned short* __restrict__ O2b) {
  __shared__ unsigned short A_lds[64][72];
  __shared__ unsigned short W_lds[128][72];
  int t = threadIdx.x;
  int r0 = blockIdx.x * 64;
  int nb0 = blockIdx.y * 128;
  int l = t & 63;
  int wave = t >> 6;
  int wr = wave >> 1, wc = wave & 1;

  floatx16 acc[2] = {{0}, {0}};

  int sar = t >> 2, sak = (t & 3) * 16;
  int arow = min(r0 + sar, N_NODES - 1);
  int swn = t >> 1, swk = (t & 1) * 32;
  const unsigned short* Wrow = &Wt[(nb0 + swn) * 256];

  for (int kb = 0; kb < 256; kb += 64) {
    uint4 av0 = *(const uint4*)&h1b[arow*256 + kb + sak];
    uint4 av1 = *(const uint4*)&h1b[arow*256 + kb + sak + 8];
    uint4 wv0 = *(const uint4*)&Wrow[kb + swk];
    uint4 wv1 = *(const uint4*)&Wrow[kb + swk + 8];
    uint4 wv2 = *(const uint4*)&Wrow[kb + swk + 16];
    uint4 wv3 = *(const uint4*)&Wrow[kb + swk + 24];
    __syncthreads();
    *(uint4*)&A_lds[sar][sak]     = av0;
    *(uint4*)&A_lds[sar][sak + 8] = av1;
    *(uint4*)&W_lds[swn][swk]      = wv0;
    *(uint4*)&W_lds[swn][swk +  8] = wv1;
    *(uint4*)&W_lds[swn][swk + 16] = wv2;
    *(uint4*)&W_lds[swn][swk + 24] = wv3;
    __syncthreads();
    #pragma unroll
    for (int ks = 0; ks < 64; ks += 16) {
      short8 af  = *(const short8*)&A_lds[wr*32 + (l & 31)][ks + 8*(l >> 5)];
      short8 bf0 = *(const short8*)&W_lds[wc*64      + (l & 31)][ks + 8*(l >> 5)];
      short8 bf1 = *(const short8*)&W_lds[wc*64 + 32 + (l & 31)][ks + 8*(l >> 5)];
      acc[0] = __builtin_amdgcn_mfma_f32_32x32x16_bf16(af, bf0, acc[0], 0, 0, 0);
      acc[1] = __builtin_amdgcn_mfma_f32_32x32x16_bf16(af, bf1, acc[1], 0, 0, 0);
    }
  }

  bool isO1 = (nb0 < 256);
  #pragma unroll
  for (int tile = 0; tile < 2; tile++) {
    int col = nb0 + wc*64 + tile*32 + (l & 31);
    float bias = isO1 ? b1[col] : b2[col - 256];
    #pragma unroll
    for (int reg = 0; reg < 16; reg++) {
      int row = (reg & 3) + 8*(reg >> 2) + 4*(l >> 5);
      int r = r0 + wr*32 + row;
      if (r < N_NODES) {
        float v = acc[tile][reg] + bias;
        if (isO1) O1b[r*256 + col] = (unsigned short)bf16rne(v);
        else      O2b[r*256 + (col - 256)] = (unsigned short)bf16rne(v);
      }
    }
  }
}

// ------- policy: bf16 MFMA phase1 (64x128), LDS hid, phase2 + exp -----------
__global__ void __launch_bounds__(256) k_policy(
    const unsigned short* __restrict__ h2b, const unsigned short* __restrict__ Wp1t,
    const float* __restrict__ bp1, const float* __restrict__ Wp2,
    const float* __restrict__ bp2, float* __restrict__ elg, float* __restrict__ tot) {
  __shared__ __align__(16) char smembuf[64 * 132 * 4];   // 33792 B union
  unsigned short* A_lds = (unsigned short*)smembuf;                  // [64][72]
  unsigned short* W_lds = (unsigned short*)(smembuf + 64*72*2);      // [128][72]
  float* hidl = (float*)smembuf;                                     // [64][132]
  __shared__ float wred[4];
  int t = threadIdx.x;
  int r0 = blockIdx.x * 64;
  int l = t & 63;
  int wave = t >> 6;
  int wr = wave >> 1, wc = wave & 1;

  floatx16 acc[2] = {{0}, {0}};

  int sar = t >> 2, sak = (t & 3) * 16;
  int arow = min(r0 + sar, N_NODES - 1);
  int swn = t >> 1, swk = (t & 1) * 32;
  const unsigned short* Wrow = &Wp1t[swn * 256];

  for (int kb = 0; kb < 256; kb += 64) {
    uint4 av0 = *(const uint4*)&h2b[arow*256 + kb + sak];
    uint4 av1 = *(const uint4*)&h2b[arow*256 + kb + sak + 8];
    uint4 wv0 = *(const uint4*)&Wrow[kb + swk];
    uint4 wv1 = *(const uint4*)&Wrow[kb + swk + 8];
    uint4 wv2 = *(const uint4*)&Wrow[kb + swk + 16];
    uint4 wv3 = *(const uint4*)&Wrow[kb + swk + 24];
    __syncthreads();
    *(uint4*)&A_lds[sar*72 + sak]     = av0;
    *(uint4*)&A_lds[sar*72 + sak + 8] = av1;
    *(uint4*)&W_lds[swn*72 + swk]      = wv0;
    *(uint4*)&W_lds[swn*72 + swk +  8] = wv1;
    *(uint4*)&W_lds[swn*72 + swk + 16] = wv2;
    *(uint4*)&W_lds[swn*72 + swk + 24] = wv3;
    __syncthreads();
    #pragma unroll
    for (int ks = 0; ks < 64; ks += 16) {
      short8 af  = *(const short8*)&A_lds[(wr*32 + (l & 31))*72 + ks + 8*(l >> 5)];
      short8 bf0 = *(const short8*)&W_lds[(wc*64      + (l & 31))*72 + ks + 8*(l >> 5)];
      short8 bf1 = *(const short8*)&W_lds[(wc*64 + 32 + (l & 31))*72 + ks + 8*(l >> 5)];
      acc[0] = __builtin_amdgcn_mfma_f32_32x32x16_bf16(af, bf0, acc[0], 0, 0, 0);
      acc[1] = __builtin_amdgcn_mfma_f32_32x32x16_bf16(af, bf1, acc[1], 0, 0, 0);
    }
  }
  __syncthreads();   // A/W dead; smem becomes hidl[64][132]
  #pragma unroll
  for (int tile = 0; tile < 2; tile++) {
    int col = wc*64 + tile*32 + (l & 31);
    float bias = bp1[col];
    #pragma unroll
    for (int reg = 0; reg < 16; reg++) {
      int row = (reg & 3) + 8*(reg >> 2) + 4*(l >> 5) + wr*32;
      hidl[row*132 + col] = fmaxf(acc[tile][reg] + bias, 0.f);
    }
  }
  __syncthreads();
  int nl = t >> 2, i = t & 3;
  float s = bp2[i];
  for (int k = 0; k < 128; k += 4) {
    float4 hv = *(const float4*)&hidl[nl*132 + k];
    s = fmaf(hv.x, Wp2[(k+0)*4 + i],
        fmaf(hv.y, Wp2[(k+1)*4 + i],
        fmaf(hv.z, Wp2[(k+2)*4 + i],
        fmaf(hv.w, Wp2[(k+3)*4 + i], s))));
  }
  int n = r0 + nl;
  float esum = 0.f;
  if (n < N_NODES) {
    float e = expf(s);
    elg[n*4 + i] = e;
    esum = e;
  }
  #pragma unroll
  for (int msk = 1; msk < 64; msk <<= 1) esum += __shfl_xor(esum, msk);
  if ((t & 63) == 0) wred[t >> 6] = esum;
  __syncthreads();
  if (t == 0) atomicAdd(tot, (wred[0] + wred[1]) + (wred[2] + wred[3]));
}

// ---------------- normalize: out = elg * (1/tot) ----------------------------
__global__ void __launch_bounds__(1024) k_sm_final(const float* __restrict__ elg,
                                                   const float* __restrict__ tot,
                                                   float* __restrict__ out) {
  int i = blockIdx.x * 1024 + threadIdx.x;
  float inv = 1.f / tot[0];
  if (i < N_NODES * 4) out[i] = elg[i] * inv;
}

extern "C" void kernel_launch(void* const* d_in, const int* in_sizes, int n_in,
                              void* d_out, int out_size, void* d_ws, size_t ws_size,
                              hipStream_t stream) {
  const float* x    = (const float*)d_in[0];
  const int*   ei   = (const int*)  d_in[1];
  const float* ea   = (const float*)d_in[2];
  const float* Wl1  = (const float*)d_in[3];
  const float* bl1  = (const float*)d_in[4];
  const float* Wr1  = (const float*)d_in[5];
  const float* br1  = (const float*)d_in[6];
  const float* We1  = (const float*)d_in[7];
  const float* att1 = (const float*)d_in[8];
  const float* bias1= (const float*)d_in[9];
  const float* g1   = (const float*)d_in[10];
  const float* be1  = (const float*)d_in[11];
  const float* Wl2  = (const float*)d_in[12];
  const float* bl2  = (const float*)d_in[13];
  const float* Wr2  = (const float*)d_in[14];
  const float* br2  = (const float*)d_in[15];
  const float* We2  = (const float*)d_in[16];
  const float* att2 = (const float*)d_in[17];
  const float* bias2= (const float*)d_in[18];
  const float* g2   = (const float*)d_in[19];
  const float* be2  = (const float*)d_in[20];
  const float* Wp1  = (const float*)d_in[21];
  const float* bp1  = (const float*)d_in[22];
  const float* Wp2  = (const float*)d_in[23];
  const float* bp2  = (const float*)d_in[24];
  float* out = (float*)d_out;

  const int* srcp = ei;
  const int* dstp = ei + N_EDGES;

  // workspace layout: [pdeg | tot] zeroed in ONE memset
  unsigned long long* pdeg = (unsigned long long*)d_ws;    // 10240 x 8B
  float* tot   = (float*)(pdeg + 10240);     // 16
  int*   offs  = (int*)(tot + 16);           // 10240
  float* lattr = (float*)(offs + 10240);     // 10240
  int*   rank  = (int*)(lattr + 10240);      // 320192
  int2*  cpk   = (int2*)(rank + 320192);     // CPK_CAP int2 (pad zeroed by scatter)
  unsigned short* h1b   = (unsigned short*)(cpk + CPK_CAP);  // 10000x256 bf16
  unsigned short* h2b   = h1b;               // conv2 output aliases (h1b dead)
  unsigned short* xl2bf = h1b + 2560000;     // 10000x256 bf16
  unsigned short* xr2b  = xl2bf + 2560000;   // 10000x256 bf16
  float* elg   = (float*)(xr2b + 2560000);   // 40960
  unsigned short* Wt   = (unsigned short*)(elg + 40960);   // 512x256 bf16
  unsigned short* Wp1t = Wt + 512*256;                     // 128x256 bf16

  hipMemsetAsync(pdeg, 0, 10240 * 8 + 64, stream);

  k_front  <<<1250 + 192, 256, 0, stream>>>(dstp, ea, pdeg, rank,
                                            Wl2, Wr2, Wp1, Wt, Wp1t);
  k_scan   <<<1, 256, 0, stream>>>(pdeg, offs, lattr);
  k_scatter<<<(CPK_CAP + 255)/256, 256, 0, stream>>>(srcp, dstp, ea, lattr, offs,
                                                     rank, cpk);
  k_conv1  <<<N_NODES/4, 256, 0, stream>>>(x, Wl1, bl1, Wr1, br1, We1, att1,
                                           offs, cpk, bias1, g1, be1, (uint2*)h1b);
  k_gemm_dual<<<dim3(157, 4), 256, 0, stream>>>(h1b, Wt, bl2, br2, xl2bf, xr2b);
  k_conv2  <<<N_NODES/4, 256, 0, stream>>>((const uint2*)xl2bf, (const uint2*)xr2b,
                                           offs, cpk, We2, att2, bias2, g2, be2,
                                           (uint2*)h2b);
  k_policy <<<157, 256, 0, stream>>>(h2b, Wp1t, bp1, Wp2, bp2, elg, tot);
  k_sm_final<<<40, 1024, 0, stream>>>(elg, tot, out);
}